// Round 16
// baseline (259.605 us; speedup 1.0000x reference)
//
#include <hip/hip_runtime.h>
#include <cstdint>
#include <cstddef>

#define T_TOK 8192
#define DDIM 1024
#define FDIM 2048
#define NEXP 8

typedef _Float16 f16x8 __attribute__((ext_vector_type(8)));
typedef _Float16 f16x4 __attribute__((ext_vector_type(4)));
typedef float f32x4 __attribute__((ext_vector_type(4)));

__device__ __forceinline__ void gl_lds16(const void* g, void* s) {
  __builtin_amdgcn_global_load_lds(
      (const __attribute__((address_space(1))) void*)g,
      (__attribute__((address_space(3))) void*)s, 16, 0, 0);
}

#define WAITVM(n) asm volatile("s_waitcnt vmcnt(" #n ")" ::: "memory")

// Abramowitz-Stegun 7.1.26, |err| <= 1.5e-7
__device__ __forceinline__ float fast_erf(float x) {
  float ax = __builtin_fabsf(x);
  float t = __builtin_amdgcn_rcpf(1.0f + 0.3275911f * ax);
  float y = t * (0.254829592f +
           t * (-0.284496736f +
           t * (1.421413741f +
           t * (-1.453152027f +
           t * 1.061405429f))));
  float r = 1.0f - y * __expf(-ax * ax);
  return __builtin_copysignf(r, x);
}

// ============ fused prep: gate (1-in-9) + fcW transpose ==================
// grid = 9216 blocks x 256:  1024 gate + 8192 fcW tiles
__global__ __launch_bounds__(256) void k_prep(
    const float* __restrict__ x, const float* __restrict__ gW,
    const float* __restrict__ gb, int* __restrict__ idx,
    float* __restrict__ wgt, _Float16* __restrict__ Xh,
    const float* __restrict__ fcW, _Float16* __restrict__ fcWt) {
  __shared__ _Float16 tile[64][72];
  int bid = blockIdx.x;

  if (bid % 9 == 0) {
    // ---------------- gate block ----------------
    int gblk = bid / 9;                    // 0..1023
    int wid = threadIdx.x >> 6, lane = threadIdx.x & 63;
    int wave = gblk * 4 + wid;
    int t0 = wave * 2;

    double acc[2][NEXP];
#pragma unroll
    for (int tk = 0; tk < 2; ++tk)
#pragma unroll
      for (int e = 0; e < NEXP; ++e) acc[tk][e] = 0.0;

#pragma unroll
    for (int ch = 0; ch < 4; ++ch) {
      int dbase = ch * 256 + 4 * lane;
      const f32x4* wp = (const f32x4*)(gW + (size_t)dbase * NEXP);
      f32x4 wv[8];
#pragma unroll
      for (int i = 0; i < 8; ++i) wv[i] = wp[i];
#pragma unroll
      for (int tk = 0; tk < 2; ++tk) {
        f32x4 xv = *(const f32x4*)(x + (size_t)(t0 + tk) * DDIM + dbase);
        f16x4 h = { (_Float16)xv[0], (_Float16)xv[1], (_Float16)xv[2], (_Float16)xv[3] };
        *(f16x4*)(Xh + (size_t)(t0 + tk) * DDIM + dbase) = h;
#pragma unroll
        for (int j = 0; j < 4; ++j) {
          double xd = (double)xv[j];
#pragma unroll
          for (int e = 0; e < NEXP; ++e)
            acc[tk][e] += xd * (double)wv[2 * j + (e >> 2)][e & 3];
        }
      }
    }

#pragma unroll
    for (int off = 32; off > 0; off >>= 1) {
#pragma unroll
      for (int tk = 0; tk < 2; ++tk)
#pragma unroll
        for (int e = 0; e < NEXP; ++e)
          acc[tk][e] += __shfl_xor(acc[tk][e], off, 64);
    }
    if (lane == 0) {
#pragma unroll
      for (int tk = 0; tk < 2; ++tk) {
        double mx = -1e300; int am = 0;
#pragma unroll
        for (int e = 0; e < NEXP; ++e) {
          acc[tk][e] += (double)gb[e];
          if (acc[tk][e] > mx) { mx = acc[tk][e]; am = e; }
        }
        double s = 0.0;
#pragma unroll
        for (int e = 0; e < NEXP; ++e) s += exp(acc[tk][e] - mx);
        idx[t0 + tk] = am;
        wgt[t0 + tk] = (float)(1.0 / s);
      }
    }
    return;
  }

  // ---------------- fcW transpose tile: [8][1024][4096] -> [8][4096][1024]
  int t = bid - bid / 9 - 1;               // 0..8191
  int z = t >> 10, tt = t & 1023;
  const int R = 1024, C = 4096;
  int r0 = ((tt >> 6) & 15) * 64, c0 = (tt & 63) * 64;
  size_t base = (size_t)z * (size_t)R * (size_t)C;
  const float* src = fcW;
  _Float16* dst = fcWt;

  int th = threadIdx.x;
  int lrr = th >> 4, lc4 = th & 15;
#pragma unroll
  for (int i = 0; i < 4; ++i) {
    int r = lrr + i * 16;
    float4 v = *(const float4*)(src + base + (size_t)(r0 + r) * C + c0 + lc4 * 4);
    tile[r][lc4 * 4 + 0] = (_Float16)v.x;
    tile[r][lc4 * 4 + 1] = (_Float16)v.y;
    tile[r][lc4 * 4 + 2] = (_Float16)v.z;
    tile[r][lc4 * 4 + 3] = (_Float16)v.w;
  }
  __syncthreads();
  int oc = th >> 2, ch = th & 3;
#pragma unroll
  for (int i = 0; i < 2; ++i) {
    int chunk = ch + i * 4;
    f16x8 v;
#pragma unroll
    for (int j = 0; j < 8; ++j) v[j] = tile[chunk * 8 + j][oc];
    *(f16x8*)(dst + base + (size_t)(c0 + oc) * R + r0 + chunk * 8) = v;
  }
}

// ======= route (block 0) + oW transpose (blocks 1..4096), 1024 thr =======
__global__ __launch_bounds__(1024) void k_route_oT(
    const int* __restrict__ idx, const float* __restrict__ wgt,
    int* __restrict__ perm, int* __restrict__ counts_out,
    int* __restrict__ offs_out, float* __restrict__ loss_out,
    const float* __restrict__ oW, _Float16* __restrict__ outWt) {
  __shared__ int cnt_ws[16][NEXP];
  __shared__ float sc_ws[16][NEXP];
  __shared__ int wprefix[16][NEXP];
  __shared__ int base_s[NEXP];
  __shared__ _Float16 tile[64][72];

  int tid = threadIdx.x;

  if (blockIdx.x != 0) {
    // ------- oW transpose tile: [8][2048][1024] -> [8][1024][2048] -------
    int t2 = blockIdx.x - 1;               // 0..4095
    int z = t2 >> 9, tt = t2 & 511;
    const int R = 2048, C = 1024;
    int r0 = (tt >> 4) * 64, c0 = (tt & 15) * 64;
    size_t base = (size_t)z * (size_t)R * (size_t)C;

    int r = tid >> 4, c4 = tid & 15;       // 64 rows x 16 float4-chunks
    float4 v = *(const float4*)(oW + base + (size_t)(r0 + r) * C + c0 + c4 * 4);
    tile[r][c4 * 4 + 0] = (_Float16)v.x;
    tile[r][c4 * 4 + 1] = (_Float16)v.y;
    tile[r][c4 * 4 + 2] = (_Float16)v.z;
    tile[r][c4 * 4 + 3] = (_Float16)v.w;
    __syncthreads();
    int oc = tid >> 4, ch = tid & 15;      // 64 out-rows x 16 f16x4-chunks
    f16x4 o;
#pragma unroll
    for (int j = 0; j < 4; ++j) o[j] = tile[ch * 4 + j][oc];
    *(f16x4*)(outWt + base + (size_t)(c0 + oc) * R + r0 + ch * 4) = o;
    return;
  }

  // --------------------------- route block ------------------------------
  int w = tid >> 6, lane = tid & 63;

  int c_e[NEXP];
  float s_e[NEXP];
#pragma unroll
  for (int e = 0; e < NEXP; ++e) { c_e[e] = 0; s_e[e] = 0.f; }
  for (int c = 0; c < 8; ++c) {
    int t = c * 1024 + tid;
    int my = idx[t];
    float mw = wgt[t];
#pragma unroll
    for (int e = 0; e < NEXP; ++e) {
      unsigned long long m = __ballot(my == e);
      if (lane == 0) c_e[e] += (int)__popcll(m);
      s_e[e] += (my == e) ? mw : 0.f;
    }
  }
#pragma unroll
  for (int off = 32; off > 0; off >>= 1) {
#pragma unroll
    for (int e = 0; e < NEXP; ++e) s_e[e] += __shfl_xor(s_e[e], off, 64);
  }
  if (lane == 0) {
#pragma unroll
    for (int e = 0; e < NEXP; ++e) { cnt_ws[w][e] = c_e[e]; sc_ws[w][e] = s_e[e]; }
  }
  __syncthreads();
  if (tid == 0) {
    int tot[NEXP]; float sct[NEXP];
#pragma unroll
    for (int e = 0; e < NEXP; ++e) { tot[e] = 0; sct[e] = 0.f; }
    for (int ww = 0; ww < 16; ++ww)
#pragma unroll
      for (int e = 0; e < NEXP; ++e) { tot[e] += cnt_ws[ww][e]; sct[e] += sc_ws[ww][e]; }
    int off = 0; float loss = 0.f;
#pragma unroll
    for (int e = 0; e < NEXP; ++e) {
      offs_out[e] = off; counts_out[e] = tot[e];
      base_s[e] = off;
      off += tot[e];
      float usage = sct[e] / ((float)tot[e] + 1e-8f);
      float d = usage - (1.0f / NEXP);
      loss += d * d;
    }
    loss_out[0] = loss;
  }
  __syncthreads();

  unsigned long long lt_mask = ((unsigned long long)1 << lane) - 1ull;
  for (int c = 0; c < 8; ++c) {
    int t = c * 1024 + tid;
    int my = idx[t];
    int rank_w = 0;
    int wcnt[NEXP];
#pragma unroll
    for (int e = 0; e < NEXP; ++e) {
      unsigned long long m = __ballot(my == e);
      if (my == e) rank_w = (int)__popcll(m & lt_mask);
      wcnt[e] = (int)__popcll(m);
    }
    if (lane == 0) {
#pragma unroll
      for (int e = 0; e < NEXP; ++e) cnt_ws[w][e] = wcnt[e];
    }
    __syncthreads();
    if (tid < 128) {
      int ww = tid >> 3, e = tid & 7;
      int p = 0;
      for (int w2 = 0; w2 < 16; ++w2) if (w2 < ww) p += cnt_ws[w2][e];
      wprefix[ww][e] = p;
    }
    __syncthreads();
    int pos = base_s[my] + wprefix[w][my] + rank_w;
    perm[pos] = t;
    __syncthreads();
    if (tid < 8) base_s[tid] += wprefix[15][tid] + cnt_ws[15][tid];
    __syncthreads();
  }
}

// ------ GEMM1 + GLU (128x(64+64), BK=32, 3-buf, counted vmcnt) — R14 -----
// grid: x = 32 (n-panels of 64), y = 128 (e*16 + mi), 256 thr
__global__ __launch_bounds__(256) void k_gemm1_glu(
    const _Float16* __restrict__ Xh, const _Float16* __restrict__ Wt,
    const float* __restrict__ fcb, const int* __restrict__ offs,
    const int* __restrict__ counts, const int* __restrict__ perm,
    _Float16* __restrict__ G) {
  // bijective XCD swizzle over nwg = 4096
  int orig = blockIdx.y * 32 + blockIdx.x;
  int swz = (orig & 7) * 512 + (orig >> 3);
  int mx = swz & 31, my = swz >> 5;
  int e = my >> 4;
  int m0 = (my & 15) * 128;
  int n_e = counts[e];
  if (m0 >= n_e) return;
  int seg = offs[e];
  int n0 = mx * 64;

  __shared__ __align__(16) _Float16 As[3][128][32];    // 24 KB
  __shared__ __align__(16) _Float16 B1s[3][64][32];    // 12 KB
  __shared__ __align__(16) _Float16 B2s[3][64][32];    // 12 KB

  int tid = threadIdx.x, wid = tid >> 6, lane = tid & 63;
  int wm = wid >> 1, wn = wid & 1;

  const _Float16* We = Wt + (size_t)e * (4096ull * 1024ull);
  const float* fcbe = fcb + e * 4096;

  int srow = tid >> 2;
  int scol = ((tid & 3) ^ ((tid >> 3) & 3)) * 8;
  const _Float16* gA[2];
#pragma unroll
  for (int s = 0; s < 2; ++s) {
    int rowp = min(seg + m0 + s * 64 + srow, T_TOK - 1);
    gA[s] = Xh + (size_t)perm[rowp] * DDIM + scol;
  }
  const _Float16* gB1 = We + (size_t)(n0 + srow) * DDIM + scol;
  const _Float16* gB2 = We + (size_t)(2048 + n0 + srow) * DDIM + scol;

  f32x4 acc1[4][2], acc2[4][2];
#pragma unroll
  for (int a = 0; a < 4; ++a)
#pragma unroll
    for (int b = 0; b < 2; ++b) {
      acc1[a][b] = (f32x4){0.f, 0.f, 0.f, 0.f};
      acc2[a][b] = (f32x4){0.f, 0.f, 0.f, 0.f};
    }

  int lr = lane & 15, g = lane >> 4;
  int aoff[4], boff[2];
#pragma unroll
  for (int mf = 0; mf < 4; ++mf) {
    int r = wm * 64 + mf * 16 + lr;
    aoff[mf] = r * 64 + ((g ^ ((r >> 1) & 3)) * 16);
  }
#pragma unroll
  for (int nf = 0; nf < 2; ++nf) {
    int r = wn * 32 + nf * 16 + lr;
    boff[nf] = r * 64 + ((g ^ ((r >> 1) & 3)) * 16);
  }

#define G1_STAGE(dA, dB1, dB2, kt)                                     \
  do {                                                                 \
    int k0_ = (kt) * 32;                                               \
    gl_lds16(gA[0] + k0_, (dA) + tid * 8);                             \
    gl_lds16(gA[1] + k0_, (dA) + 2048 + tid * 8);                      \
    gl_lds16(gB1 + k0_, (dB1) + tid * 8);                              \
    gl_lds16(gB2 + k0_, (dB2) + tid * 8);                              \
  } while (0)

#define G1_COMPUTE(pAv, pB1v, pB2v)                                    \
  do {                                                                 \
    const char* pA = (const char*)(pAv);                               \
    const char* pB1 = (const char*)(pB1v);                             \
    const char* pB2 = (const char*)(pB2v);                             \
    f16x8 a[4], b1[2], b2[2];                                          \
    _Pragma("unroll")                                                  \
    for (int mf = 0; mf < 4; ++mf) a[mf] = *(const f16x8*)(pA + aoff[mf]); \
    _Pragma("unroll")                                                  \
    for (int nf = 0; nf < 2; ++nf) {                                   \
      b1[nf] = *(const f16x8*)(pB1 + boff[nf]);                        \
      b2[nf] = *(const f16x8*)(pB2 + boff[nf]);                        \
    }                                                                  \
    _Pragma("unroll")                                                  \
    for (int mf = 0; mf < 4; ++mf)                                     \
      _Pragma("unroll")                                                \
      for (int nf = 0; nf < 2; ++nf) {                                 \
        acc1[mf][nf] = __builtin_amdgcn_mfma_f32_16x16x32_f16(a[mf], b1[nf], acc1[mf][nf], 0, 0, 0); \
        acc2[mf][nf] = __builtin_amdgcn_mfma_f32_16x16x32_f16(a[mf], b2[nf], acc2[mf][nf], 0, 0, 0); \
      }                                                                \
  } while (0)

  _Float16 *cA = &As[0][0][0], *nA = &As[1][0][0], *fA = &As[2][0][0];
  _Float16 *cB1 = &B1s[0][0][0], *nB1 = &B1s[1][0][0], *fB1 = &B1s[2][0][0];
  _Float16 *cB2 = &B2s[0][0][0], *nB2 = &B2s[1][0][0], *fB2 = &B2s[2][0][0];

  G1_STAGE(cA, cB1, cB2, 0);
  G1_STAGE(nA, nB1, nB2, 1);

  for (int kt = 0; kt < 32; ++kt) {
    if (kt < 30) {
      G1_STAGE(fA, fB1, fB2, kt + 2);
      WAITVM(8);
    } else if (kt == 30) {
      WAITVM(4);
    } else {
      WAITVM(0);
    }
    __builtin_amdgcn_s_barrier();
    __builtin_amdgcn_sched_barrier(0);
    G1_COMPUTE(cA, cB1, cB2);
    __builtin_amdgcn_s_barrier();
    _Float16* t;
    t = cA; cA = nA; nA = fA; fA = t;
    t = cB1; cB1 = nB1; nB1 = fB1; fB1 = t;
    t = cB2; cB2 = nB2; nB2 = fB2; fB2 = t;
  }

  int lk4 = g * 4;
#pragma unroll
  for (int mf = 0; mf < 4; ++mf) {
#pragma unroll
    for (int i = 0; i < 4; ++i) {
      int pl = m0 + wm * 64 + mf * 16 + lk4 + i;
      if (pl >= n_e) continue;
      size_t grow = (size_t)(seg + pl) * FDIM;
#pragma unroll
      for (int nf = 0; nf < 2; ++nf) {
        int col = n0 + wn * 32 + nf * 16 + lr;
        float x1 = acc1[mf][nf][i] + fcbe[col];
        float x2v = acc2[mf][nf][i] + fcbe[2048 + col];
        float gg = x1 * x2v * 0.5f * (1.0f + fast_erf(x2v * 0.70710678118654752f));
        G[grow + col] = (_Float16)gg;
      }
    }
  }
}

// ---------------- GEMM2 (128x128, BK=32, 3-buf, counted vmcnt) — R8 ------
// grid: x = 8 (n-panels of 128), y = 128 (e*16 + mi), 256 thr
__global__ __launch_bounds__(256) void k_gemm2_out(
    const _Float16* __restrict__ G, const _Float16* __restrict__ Vt,
    const float* __restrict__ ob, const int* __restrict__ offs,
    const int* __restrict__ counts, const int* __restrict__ perm,
    const float* __restrict__ wgt, float* __restrict__ out) {
  int orig = blockIdx.y * 8 + blockIdx.x;
  int swz = (orig & 7) * 128 + (orig >> 3);
  int mx = swz & 7, my = swz >> 3;
  int e = my >> 4;
  int m0 = (my & 15) * 128;
  int n_e = counts[e];
  if (m0 >= n_e) return;
  int seg = offs[e];
  int n0 = mx * 128;

  __shared__ __align__(16) _Float16 As[3][128][32];   // 24 KB
  __shared__ __align__(16) _Float16 Bs[3][128][32];   // 24 KB

  int tid = threadIdx.x, wid = tid >> 6, lane = tid & 63;
  int wm = wid >> 1, wn = wid & 1;
  const _Float16* Ve = Vt + (size_t)e * (1024ull * 2048ull);
  const float* obe = ob + e * 1024;

  int srow = tid >> 2;
  int scol = ((tid & 3) ^ ((tid >> 3) & 3)) * 8;
  const _Float16* gA[2]; const _Float16* gB[2];
#pragma unroll
  for (int s = 0; s < 2; ++s) {
    int r = min(seg + m0 + s * 64 + srow, T_TOK - 1);
    gA[s] = G + (size_t)r * FDIM + scol;
    gB[s] = Ve + (size_t)(n0 + s * 64 + srow) * FDIM + scol;
  }

  f32x4 acc[4][4];
#pragma unroll
  for (int a = 0; a < 4; ++a)
#pragma unroll
    for (int b = 0; b < 4; ++b) acc[a][b] = (f32x4){0.f, 0.f, 0.f, 0.f};

  int lr = lane & 15, g = lane >> 4;
  int aoff[4], boff[4];
#pragma unroll
  for (int mf = 0; mf < 4; ++mf) {
    int r = wm * 64 + mf * 16 + lr;
    aoff[mf] = r * 64 + ((g ^ ((r >> 1) & 3)) * 16);
  }
#pragma unroll
  for (int nf = 0; nf < 4; ++nf) {
    int r = wn * 64 + nf * 16 + lr;
    boff[nf] = r * 64 + ((g ^ ((r >> 1) & 3)) * 16);
  }

#define G2_STAGE(dA, dB, kt)                                           \
  do {                                                                 \
    int k0_ = (kt) * 32;                                               \
    gl_lds16(gA[0] + k0_, (dA) + tid * 8);                             \
    gl_lds16(gA[1] + k0_, (dA) + 2048 + tid * 8);                      \
    gl_lds16(gB[0] + k0_, (dB) + tid * 8);                             \
    gl_lds16(gB[1] + k0_, (dB) + 2048 + tid * 8);                      \
  } while (0)

#define G2_COMPUTE(pAv, pBv)                                           \
  do {                                                                 \
    const char* pA = (const char*)(pAv);                               \
    const char* pB = (const char*)(pBv);                               \
    f16x8 a[4], b[4];                                                  \
    _Pragma("unroll")                                                  \
    for (int mf = 0; mf < 4; ++mf) a[mf] = *(const f16x8*)(pA + aoff[mf]); \
    _Pragma("unroll")                                                  \
    for (int nf = 0; nf < 4; ++nf) b[nf] = *(const f16x8*)(pB + boff[nf]); \
    _Pragma("unroll")                                                  \
    for (int mf = 0; mf < 4; ++mf)                                     \
      _Pragma("unroll")                                                \
      for (int nf = 0; nf < 4; ++nf)                                   \
        acc[mf][nf] = __builtin_amdgcn_mfma_f32_16x16x32_f16(a[mf], b[nf], acc[mf][nf], 0, 0, 0); \
  } while (0)

  _Float16 *cA = &As[0][0][0], *nA = &As[1][0][0], *fA = &As[2][0][0];
  _Float16 *cB = &Bs[0][0][0], *nB = &Bs[1][0][0], *fB = &Bs[2][0][0];

  G2_STAGE(cA, cB, 0);
  G2_STAGE(nA, nB, 1);

  for (int kt = 0; kt < 64; ++kt) {
    if (kt < 62) {
      G2_STAGE(fA, fB, kt + 2);
      WAITVM(8);
    } else if (kt == 62) {
      WAITVM(4);
    } else {
      WAITVM(0);
    }
    __builtin_amdgcn_s_barrier();
    __builtin_amdgcn_sched_barrier(0);
    G2_COMPUTE(cA, cB);
    __builtin_amdgcn_s_barrier();
    _Float16* t;
    t = cA; cA = nA; nA = fA; fA = t;
    t = cB; cB = nB; nB = fB; fB = t;
  }

  int lk4 = g * 4;
#pragma unroll
  for (int mf = 0; mf < 4; ++mf) {
#pragma unroll
    for (int i = 0; i < 4; ++i) {
      int pl = m0 + wm * 64 + mf * 16 + lk4 + i;
      if (pl >= n_e) continue;
      int p = seg + pl;
      int t = perm[p];
      float wv = wgt[t];
      float* orow = out + (size_t)t * DDIM;
#pragma unroll
      for (int nf = 0; nf < 4; ++nf) {
        int col = n0 + wn * 64 + nf * 16 + lr;
        orow[col] = (acc[mf][nf][i] + obe[col]) * wv;
      }
    }
  }
}

extern "C" void kernel_launch(void* const* d_in, const int* in_sizes, int n_in,
                              void* d_out, int out_size, void* d_ws, size_t ws_size,
                              hipStream_t stream) {
  const float* x   = (const float*)d_in[0];
  const float* gW  = (const float*)d_in[1];
  const float* gb  = (const float*)d_in[2];
  const float* fcW = (const float*)d_in[3];
  const float* fcb = (const float*)d_in[4];
  const float* oW  = (const float*)d_in[5];
  const float* ob  = (const float*)d_in[6];
  float* out = (float*)d_out;

  char* p = (char*)d_ws;
  _Float16* fcWt  = (_Float16*)p; p += (size_t)NEXP * 4096 * 1024 * 2;
  _Float16* outWt = (_Float16*)p; p += (size_t)NEXP * 1024 * 2048 * 2;
  _Float16* Xh    = (_Float16*)p; p += (size_t)T_TOK * DDIM * 2;
  _Float16* G     = (_Float16*)p; p += (size_t)T_TOK * FDIM * 2;
  int*   idx     = (int*)p;   p += T_TOK * 4;
  float* wgt     = (float*)p; p += T_TOK * 4;
  int*   perm    = (int*)p;   p += T_TOK * 4;
  int*   counts  = (int*)p;   p += 64;
  int*   offs    = (int*)p;   p += 64;

  // prep: gate + fcW transpose
  k_prep<<<9216, 256, 0, stream>>>(x, gW, gb, idx, wgt, Xh, fcW, fcWt);
  // route (1 block) hidden under oW transpose (4096 blocks)
  k_route_oT<<<4097, 1024, 0, stream>>>(idx, wgt, perm, counts, offs,
                                        out + (size_t)T_TOK * DDIM, oW, outWt);
  k_gemm1_glu<<<dim3(32, 128), 256, 0, stream>>>(Xh, fcWt, fcb, offs, counts, perm, G);
  k_gemm2_out<<<dim3(8, 128), 256, 0, stream>>>(G, outWt, ob, offs, counts, perm, wgt, out);
}

// Round 17
// 257.159 us; speedup vs baseline: 1.0095x; 1.0095x over previous
//
#include <hip/hip_runtime.h>
#include <cstdint>
#include <cstddef>

#define T_TOK 8192
#define DDIM 1024
#define FDIM 2048
#define NEXP 8

typedef _Float16 f16x8 __attribute__((ext_vector_type(8)));
typedef _Float16 f16x4 __attribute__((ext_vector_type(4)));
typedef float f32x4 __attribute__((ext_vector_type(4)));

__device__ __forceinline__ void gl_lds16(const void* g, void* s) {
  __builtin_amdgcn_global_load_lds(
      (const __attribute__((address_space(1))) void*)g,
      (__attribute__((address_space(3))) void*)s, 16, 0, 0);
}

#define WAITVM(n) asm volatile("s_waitcnt vmcnt(" #n ")" ::: "memory")

// Abramowitz-Stegun 7.1.26, |err| <= 1.5e-7
__device__ __forceinline__ float fast_erf(float x) {
  float ax = __builtin_fabsf(x);
  float t = __builtin_amdgcn_rcpf(1.0f + 0.3275911f * ax);
  float y = t * (0.254829592f +
           t * (-0.284496736f +
           t * (1.421413741f +
           t * (-1.453152027f +
           t * 1.061405429f))));
  float r = 1.0f - y * __expf(-ax * ax);
  return __builtin_copysignf(r, x);
}

// TSTRIDE = 66 f16 = 132 B = 33 banks == 1 (mod 32)  -> conflict-free cols
#define TSTRIDE 66

// ============ fused prep: gate (1-in-9) + fcW transpose ==================
// grid = 9216 blocks x 256:  1024 gate + 8192 fcW tiles
__global__ __launch_bounds__(256) void k_prep(
    const float* __restrict__ x, const float* __restrict__ gW,
    const float* __restrict__ gb, int* __restrict__ idx,
    float* __restrict__ wgt, _Float16* __restrict__ Xh,
    const float* __restrict__ fcW, _Float16* __restrict__ fcWt) {
  __shared__ _Float16 tile[64][TSTRIDE];
  int bid = blockIdx.x;

  if (bid % 9 == 0) {
    // ---------------- gate block ----------------
    int gblk = bid / 9;                    // 0..1023
    int wid = threadIdx.x >> 6, lane = threadIdx.x & 63;
    int wave = gblk * 4 + wid;
    int t0 = wave * 2;

    double acc[2][NEXP];
#pragma unroll
    for (int tk = 0; tk < 2; ++tk)
#pragma unroll
      for (int e = 0; e < NEXP; ++e) acc[tk][e] = 0.0;

#pragma unroll
    for (int ch = 0; ch < 4; ++ch) {
      int dbase = ch * 256 + 4 * lane;
      const f32x4* wp = (const f32x4*)(gW + (size_t)dbase * NEXP);
      f32x4 wv[8];
#pragma unroll
      for (int i = 0; i < 8; ++i) wv[i] = wp[i];
#pragma unroll
      for (int tk = 0; tk < 2; ++tk) {
        f32x4 xv = *(const f32x4*)(x + (size_t)(t0 + tk) * DDIM + dbase);
        f16x4 h = { (_Float16)xv[0], (_Float16)xv[1], (_Float16)xv[2], (_Float16)xv[3] };
        *(f16x4*)(Xh + (size_t)(t0 + tk) * DDIM + dbase) = h;
#pragma unroll
        for (int j = 0; j < 4; ++j) {
          double xd = (double)xv[j];
#pragma unroll
          for (int e = 0; e < NEXP; ++e)
            acc[tk][e] += xd * (double)wv[2 * j + (e >> 2)][e & 3];
        }
      }
    }

#pragma unroll
    for (int off = 32; off > 0; off >>= 1) {
#pragma unroll
      for (int tk = 0; tk < 2; ++tk)
#pragma unroll
        for (int e = 0; e < NEXP; ++e)
          acc[tk][e] += __shfl_xor(acc[tk][e], off, 64);
    }
    if (lane == 0) {
#pragma unroll
      for (int tk = 0; tk < 2; ++tk) {
        double mx = -1e300; int am = 0;
#pragma unroll
        for (int e = 0; e < NEXP; ++e) {
          acc[tk][e] += (double)gb[e];
          if (acc[tk][e] > mx) { mx = acc[tk][e]; am = e; }
        }
        double s = 0.0;
#pragma unroll
        for (int e = 0; e < NEXP; ++e) s += exp(acc[tk][e] - mx);
        idx[t0 + tk] = am;
        wgt[t0 + tk] = (float)(1.0 / s);
      }
    }
    return;
  }

  // ---------------- fcW transpose tile: [8][1024][4096] -> [8][4096][1024]
  int t = bid - bid / 9 - 1;               // 0..8191
  int z = t >> 10, tt = t & 1023;
  const int R = 1024, C = 4096;
  int r0 = ((tt >> 6) & 15) * 64, c0 = (tt & 63) * 64;
  size_t base = (size_t)z * (size_t)R * (size_t)C;

  int th = threadIdx.x;
  int lrr = th >> 4, lc4 = th & 15;
#pragma unroll
  for (int i = 0; i < 4; ++i) {
    int r = lrr + i * 16;
    float4 v = *(const float4*)(fcW + base + (size_t)(r0 + r) * C + c0 + lc4 * 4);
    tile[r][lc4 * 4 + 0] = (_Float16)v.x;
    tile[r][lc4 * 4 + 1] = (_Float16)v.y;
    tile[r][lc4 * 4 + 2] = (_Float16)v.z;
    tile[r][lc4 * 4 + 3] = (_Float16)v.w;
  }
  __syncthreads();
  int oc = th >> 2, ch = th & 3;
#pragma unroll
  for (int i = 0; i < 2; ++i) {
    int chunk = ch + i * 4;
    f16x8 v;
#pragma unroll
    for (int j = 0; j < 8; ++j) v[j] = tile[chunk * 8 + j][oc];
    *(f16x8*)(fcWt + base + (size_t)(c0 + oc) * R + r0 + chunk * 8) = v;
  }
}

// ---------------- routing: counts/offsets/loss + stable rank scatter ------
__global__ __launch_bounds__(1024) void k_route(
    const int* __restrict__ idx, const float* __restrict__ wgt,
    int* __restrict__ perm, int* __restrict__ counts_out,
    int* __restrict__ offs_out, float* __restrict__ loss_out) {
  __shared__ int cnt_ws[16][NEXP];
  __shared__ float sc_ws[16][NEXP];
  __shared__ int wprefix[16][NEXP];
  __shared__ int base[NEXP];

  int tid = threadIdx.x, w = tid >> 6, lane = tid & 63;

  int c_e[NEXP];
  float s_e[NEXP];
#pragma unroll
  for (int e = 0; e < NEXP; ++e) { c_e[e] = 0; s_e[e] = 0.f; }
  for (int c = 0; c < 8; ++c) {
    int t = c * 1024 + tid;
    int my = idx[t];
    float mw = wgt[t];
#pragma unroll
    for (int e = 0; e < NEXP; ++e) {
      unsigned long long m = __ballot(my == e);
      if (lane == 0) c_e[e] += (int)__popcll(m);
      s_e[e] += (my == e) ? mw : 0.f;
    }
  }
#pragma unroll
  for (int off = 32; off > 0; off >>= 1) {
#pragma unroll
    for (int e = 0; e < NEXP; ++e) s_e[e] += __shfl_xor(s_e[e], off, 64);
  }
  if (lane == 0) {
#pragma unroll
    for (int e = 0; e < NEXP; ++e) { cnt_ws[w][e] = c_e[e]; sc_ws[w][e] = s_e[e]; }
  }
  __syncthreads();
  if (tid == 0) {
    int tot[NEXP]; float sct[NEXP];
#pragma unroll
    for (int e = 0; e < NEXP; ++e) { tot[e] = 0; sct[e] = 0.f; }
    for (int ww = 0; ww < 16; ++ww)
#pragma unroll
      for (int e = 0; e < NEXP; ++e) { tot[e] += cnt_ws[ww][e]; sct[e] += sc_ws[ww][e]; }
    int off = 0; float loss = 0.f;
#pragma unroll
    for (int e = 0; e < NEXP; ++e) {
      offs_out[e] = off; counts_out[e] = tot[e];
      base[e] = off;
      off += tot[e];
      float usage = sct[e] / ((float)tot[e] + 1e-8f);
      float d = usage - (1.0f / NEXP);
      loss += d * d;
    }
    loss_out[0] = loss;
  }
  __syncthreads();

  unsigned long long lt_mask = ((unsigned long long)1 << lane) - 1ull;
  for (int c = 0; c < 8; ++c) {
    int t = c * 1024 + tid;
    int my = idx[t];
    int rank_w = 0;
    int wcnt[NEXP];
#pragma unroll
    for (int e = 0; e < NEXP; ++e) {
      unsigned long long m = __ballot(my == e);
      if (my == e) rank_w = (int)__popcll(m & lt_mask);
      wcnt[e] = (int)__popcll(m);
    }
    if (lane == 0) {
#pragma unroll
      for (int e = 0; e < NEXP; ++e) cnt_ws[w][e] = wcnt[e];
    }
    __syncthreads();
    if (tid < 128) {
      int ww = tid >> 3, e = tid & 7;
      int p = 0;
      for (int w2 = 0; w2 < 16; ++w2) if (w2 < ww) p += cnt_ws[w2][e];
      wprefix[ww][e] = p;
    }
    __syncthreads();
    int pos = base[my] + wprefix[w][my] + rank_w;
    perm[pos] = t;
    __syncthreads();
    if (tid < 8) base[tid] += wprefix[15][tid] + cnt_ws[15][tid];
    __syncthreads();
  }
}

// ------ GEMM1 + GLU (128x(64+64), BK=32, 3-buf, counted vmcnt) -----------
// grid: x = 32, y = 0..127 GEMM (e*16 + mi); y = 128..255 oW-transpose tiles
__global__ __launch_bounds__(256) void k_gemm1_glu(
    const _Float16* __restrict__ Xh, const _Float16* __restrict__ Wt,
    const float* __restrict__ fcb, const int* __restrict__ offs,
    const int* __restrict__ counts, const int* __restrict__ perm,
    _Float16* __restrict__ G,
    const float* __restrict__ oW, _Float16* __restrict__ outWt) {
  __shared__ __align__(16) _Float16 As[3][128][32];    // 24 KB
  __shared__ __align__(16) _Float16 B1s[3][64][32];    // 12 KB
  __shared__ __align__(16) _Float16 B2s[3][64][32];    // 12 KB

  if (blockIdx.y >= 128) {
    // -------- oW transpose tile: [8][2048][1024] -> [8][1024][2048] ------
    // scratch (stride 66 -> conflict-free): 64*66 f16 = 8448 <= 12288 in As
    _Float16* tl = &As[0][0][0];
    int t2 = (blockIdx.y - 128) * 32 + blockIdx.x;   // 0..4095
    int z = t2 >> 9, tt = t2 & 511;
    const int R = 2048, C = 1024;
    int r0 = (tt >> 4) * 64, c0 = (tt & 15) * 64;
    size_t base = (size_t)z * (size_t)R * (size_t)C;

    int th = threadIdx.x;
    int lrr = th >> 4, lc4 = th & 15;
#pragma unroll
    for (int i = 0; i < 4; ++i) {
      int r = lrr + i * 16;
      float4 v = *(const float4*)(oW + base + (size_t)(r0 + r) * C + c0 + lc4 * 4);
      tl[r * TSTRIDE + lc4 * 4 + 0] = (_Float16)v.x;
      tl[r * TSTRIDE + lc4 * 4 + 1] = (_Float16)v.y;
      tl[r * TSTRIDE + lc4 * 4 + 2] = (_Float16)v.z;
      tl[r * TSTRIDE + lc4 * 4 + 3] = (_Float16)v.w;
    }
    __syncthreads();
    int oc = th >> 2, ch = th & 3;
#pragma unroll
    for (int i = 0; i < 2; ++i) {
      int chunk = ch + i * 4;
      f16x8 v;
#pragma unroll
      for (int j = 0; j < 8; ++j) v[j] = tl[(chunk * 8 + j) * TSTRIDE + oc];
      *(f16x8*)(outWt + base + (size_t)(c0 + oc) * R + r0 + chunk * 8) = v;
    }
    return;
  }

  // bijective XCD swizzle over the GEMM sub-grid (nwg = 4096)
  int orig = blockIdx.y * 32 + blockIdx.x;
  int swz = (orig & 7) * 512 + (orig >> 3);
  int mx = swz & 31, my = swz >> 5;
  int e = my >> 4;
  int m0 = (my & 15) * 128;
  int n_e = counts[e];
  if (m0 >= n_e) return;
  int seg = offs[e];
  int n0 = mx * 64;

  int tid = threadIdx.x, wid = tid >> 6, lane = tid & 63;
  int wm = wid >> 1, wn = wid & 1;

  const _Float16* We = Wt + (size_t)e * (4096ull * 1024ull);
  const float* fcbe = fcb + e * 4096;

  int srow = tid >> 2;
  int scol = ((tid & 3) ^ ((tid >> 3) & 3)) * 8;
  const _Float16* gA[2];
#pragma unroll
  for (int s = 0; s < 2; ++s) {
    int rowp = min(seg + m0 + s * 64 + srow, T_TOK - 1);
    gA[s] = Xh + (size_t)perm[rowp] * DDIM + scol;
  }
  const _Float16* gB1 = We + (size_t)(n0 + srow) * DDIM + scol;
  const _Float16* gB2 = We + (size_t)(2048 + n0 + srow) * DDIM + scol;

  f32x4 acc1[4][2], acc2[4][2];
#pragma unroll
  for (int a = 0; a < 4; ++a)
#pragma unroll
    for (int b = 0; b < 2; ++b) {
      acc1[a][b] = (f32x4){0.f, 0.f, 0.f, 0.f};
      acc2[a][b] = (f32x4){0.f, 0.f, 0.f, 0.f};
    }

  int lr = lane & 15, g = lane >> 4;
  int aoff[4], boff[2];
#pragma unroll
  for (int mf = 0; mf < 4; ++mf) {
    int r = wm * 64 + mf * 16 + lr;
    aoff[mf] = r * 64 + ((g ^ ((r >> 1) & 3)) * 16);
  }
#pragma unroll
  for (int nf = 0; nf < 2; ++nf) {
    int r = wn * 32 + nf * 16 + lr;
    boff[nf] = r * 64 + ((g ^ ((r >> 1) & 3)) * 16);
  }

#define G1_STAGE(dA, dB1, dB2, kt)                                     \
  do {                                                                 \
    int k0_ = (kt) * 32;                                               \
    gl_lds16(gA[0] + k0_, (dA) + tid * 8);                             \
    gl_lds16(gA[1] + k0_, (dA) + 2048 + tid * 8);                      \
    gl_lds16(gB1 + k0_, (dB1) + tid * 8);                              \
    gl_lds16(gB2 + k0_, (dB2) + tid * 8);                              \
  } while (0)

#define G1_COMPUTE(pAv, pB1v, pB2v)                                    \
  do {                                                                 \
    const char* pA = (const char*)(pAv);                               \
    const char* pB1 = (const char*)(pB1v);                             \
    const char* pB2 = (const char*)(pB2v);                             \
    f16x8 a[4], b1[2], b2[2];                                          \
    _Pragma("unroll")                                                  \
    for (int mf = 0; mf < 4; ++mf) a[mf] = *(const f16x8*)(pA + aoff[mf]); \
    _Pragma("unroll")                                                  \
    for (int nf = 0; nf < 2; ++nf) {                                   \
      b1[nf] = *(const f16x8*)(pB1 + boff[nf]);                        \
      b2[nf] = *(const f16x8*)(pB2 + boff[nf]);                        \
    }                                                                  \
    _Pragma("unroll")                                                  \
    for (int mf = 0; mf < 4; ++mf)                                     \
      _Pragma("unroll")                                                \
      for (int nf = 0; nf < 2; ++nf) {                                 \
        acc1[mf][nf] = __builtin_amdgcn_mfma_f32_16x16x32_f16(a[mf], b1[nf], acc1[mf][nf], 0, 0, 0); \
        acc2[mf][nf] = __builtin_amdgcn_mfma_f32_16x16x32_f16(a[mf], b2[nf], acc2[mf][nf], 0, 0, 0); \
      }                                                                \
  } while (0)

  _Float16 *cA = &As[0][0][0], *nA = &As[1][0][0], *fA = &As[2][0][0];
  _Float16 *cB1 = &B1s[0][0][0], *nB1 = &B1s[1][0][0], *fB1 = &B1s[2][0][0];
  _Float16 *cB2 = &B2s[0][0][0], *nB2 = &B2s[1][0][0], *fB2 = &B2s[2][0][0];

  G1_STAGE(cA, cB1, cB2, 0);
  G1_STAGE(nA, nB1, nB2, 1);

  for (int kt = 0; kt < 32; ++kt) {
    if (kt < 30) {
      G1_STAGE(fA, fB1, fB2, kt + 2);
      WAITVM(8);
    } else if (kt == 30) {
      WAITVM(4);
    } else {
      WAITVM(0);
    }
    __builtin_amdgcn_s_barrier();
    __builtin_amdgcn_sched_barrier(0);
    G1_COMPUTE(cA, cB1, cB2);
    __builtin_amdgcn_s_barrier();
    _Float16* t;
    t = cA; cA = nA; nA = fA; fA = t;
    t = cB1; cB1 = nB1; nB1 = fB1; fB1 = t;
    t = cB2; cB2 = nB2; nB2 = fB2; fB2 = t;
  }

  int lk4 = g * 4;
#pragma unroll
  for (int mf = 0; mf < 4; ++mf) {
#pragma unroll
    for (int i = 0; i < 4; ++i) {
      int pl = m0 + wm * 64 + mf * 16 + lk4 + i;
      if (pl >= n_e) continue;
      size_t grow = (size_t)(seg + pl) * FDIM;
#pragma unroll
      for (int nf = 0; nf < 2; ++nf) {
        int col = n0 + wn * 32 + nf * 16 + lr;
        float x1 = acc1[mf][nf][i] + fcbe[col];
        float x2v = acc2[mf][nf][i] + fcbe[2048 + col];
        float gg = x1 * x2v * 0.5f * (1.0f + fast_erf(x2v * 0.70710678118654752f));
        G[grow + col] = (_Float16)gg;
      }
    }
  }
}

// ---------------- GEMM2 (128x128, BK=32, 3-buf, counted vmcnt) — R8 ------
// grid: x = 8 (n-panels of 128), y = 128 (e*16 + mi), 256 thr
__global__ __launch_bounds__(256) void k_gemm2_out(
    const _Float16* __restrict__ G, const _Float16* __restrict__ Vt,
    const float* __restrict__ ob, const int* __restrict__ offs,
    const int* __restrict__ counts, const int* __restrict__ perm,
    const float* __restrict__ wgt, float* __restrict__ out) {
  int orig = blockIdx.y * 8 + blockIdx.x;
  int swz = (orig & 7) * 128 + (orig >> 3);
  int mx = swz & 7, my = swz >> 3;
  int e = my >> 4;
  int m0 = (my & 15) * 128;
  int n_e = counts[e];
  if (m0 >= n_e) return;
  int seg = offs[e];
  int n0 = mx * 128;

  __shared__ __align__(16) _Float16 As[3][128][32];   // 24 KB
  __shared__ __align__(16) _Float16 Bs[3][128][32];   // 24 KB

  int tid = threadIdx.x, wid = tid >> 6, lane = tid & 63;
  int wm = wid >> 1, wn = wid & 1;
  const _Float16* Ve = Vt + (size_t)e * (1024ull * 2048ull);
  const float* obe = ob + e * 1024;

  int srow = tid >> 2;
  int scol = ((tid & 3) ^ ((tid >> 3) & 3)) * 8;
  const _Float16* gA[2]; const _Float16* gB[2];
#pragma unroll
  for (int s = 0; s < 2; ++s) {
    int r = min(seg + m0 + s * 64 + srow, T_TOK - 1);
    gA[s] = G + (size_t)r * FDIM + scol;
    gB[s] = Ve + (size_t)(n0 + s * 64 + srow) * FDIM + scol;
  }

  f32x4 acc[4][4];
#pragma unroll
  for (int a = 0; a < 4; ++a)
#pragma unroll
    for (int b = 0; b < 4; ++b) acc[a][b] = (f32x4){0.f, 0.f, 0.f, 0.f};

  int lr = lane & 15, g = lane >> 4;
  int aoff[4], boff[4];
#pragma unroll
  for (int mf = 0; mf < 4; ++mf) {
    int r = wm * 64 + mf * 16 + lr;
    aoff[mf] = r * 64 + ((g ^ ((r >> 1) & 3)) * 16);
  }
#pragma unroll
  for (int nf = 0; nf < 4; ++nf) {
    int r = wn * 64 + nf * 16 + lr;
    boff[nf] = r * 64 + ((g ^ ((r >> 1) & 3)) * 16);
  }

#define G2_STAGE(dA, dB, kt)                                           \
  do {                                                                 \
    int k0_ = (kt) * 32;                                               \
    gl_lds16(gA[0] + k0_, (dA) + tid * 8);                             \
    gl_lds16(gA[1] + k0_, (dA) + 2048 + tid * 8);                      \
    gl_lds16(gB[0] + k0_, (dB) + tid * 8);                             \
    gl_lds16(gB[1] + k0_, (dB) + 2048 + tid * 8);                      \
  } while (0)

#define G2_COMPUTE(pAv, pBv)                                           \
  do {                                                                 \
    const char* pA = (const char*)(pAv);                               \
    const char* pB = (const char*)(pBv);                               \
    f16x8 a[4], b[4];                                                  \
    _Pragma("unroll")                                                  \
    for (int mf = 0; mf < 4; ++mf) a[mf] = *(const f16x8*)(pA + aoff[mf]); \
    _Pragma("unroll")                                                  \
    for (int nf = 0; nf < 4; ++nf) b[nf] = *(const f16x8*)(pB + boff[nf]); \
    _Pragma("unroll")                                                  \
    for (int mf = 0; mf < 4; ++mf)                                     \
      _Pragma("unroll")                                                \
      for (int nf = 0; nf < 4; ++nf)                                   \
        acc[mf][nf] = __builtin_amdgcn_mfma_f32_16x16x32_f16(a[mf], b[nf], acc[mf][nf], 0, 0, 0); \
  } while (0)

  _Float16 *cA = &As[0][0][0], *nA = &As[1][0][0], *fA = &As[2][0][0];
  _Float16 *cB = &Bs[0][0][0], *nB = &Bs[1][0][0], *fB = &Bs[2][0][0];

  G2_STAGE(cA, cB, 0);
  G2_STAGE(nA, nB, 1);

  for (int kt = 0; kt < 64; ++kt) {
    if (kt < 62) {
      G2_STAGE(fA, fB, kt + 2);
      WAITVM(8);
    } else if (kt == 62) {
      WAITVM(4);
    } else {
      WAITVM(0);
    }
    __builtin_amdgcn_s_barrier();
    __builtin_amdgcn_sched_barrier(0);
    G2_COMPUTE(cA, cB);
    __builtin_amdgcn_s_barrier();
    _Float16* t;
    t = cA; cA = nA; nA = fA; fA = t;
    t = cB; cB = nB; nB = fB; fB = t;
  }

  int lk4 = g * 4;
#pragma unroll
  for (int mf = 0; mf < 4; ++mf) {
#pragma unroll
    for (int i = 0; i < 4; ++i) {
      int pl = m0 + wm * 64 + mf * 16 + lk4 + i;
      if (pl >= n_e) continue;
      int p = seg + pl;
      int t = perm[p];
      float wv = wgt[t];
      float* orow = out + (size_t)t * DDIM;
#pragma unroll
      for (int nf = 0; nf < 4; ++nf) {
        int col = n0 + wn * 64 + nf * 16 + lr;
        orow[col] = (acc[mf][nf][i] + obe[col]) * wv;
      }
    }
  }
}

extern "C" void kernel_launch(void* const* d_in, const int* in_sizes, int n_in,
                              void* d_out, int out_size, void* d_ws, size_t ws_size,
                              hipStream_t stream) {
  const float* x   = (const float*)d_in[0];
  const float* gW  = (const float*)d_in[1];
  const float* gb  = (const float*)d_in[2];
  const float* fcW = (const float*)d_in[3];
  const float* fcb = (const float*)d_in[4];
  const float* oW  = (const float*)d_in[5];
  const float* ob  = (const float*)d_in[6];
  float* out = (float*)d_out;

  char* p = (char*)d_ws;
  _Float16* fcWt  = (_Float16*)p; p += (size_t)NEXP * 4096 * 1024 * 2;
  _Float16* outWt = (_Float16*)p; p += (size_t)NEXP * 1024 * 2048 * 2;
  _Float16* Xh    = (_Float16*)p; p += (size_t)T_TOK * DDIM * 2;
  _Float16* G     = (_Float16*)p; p += (size_t)T_TOK * FDIM * 2;
  int*   idx     = (int*)p;   p += T_TOK * 4;
  float* wgt     = (float*)p; p += T_TOK * 4;
  int*   perm    = (int*)p;   p += T_TOK * 4;
  int*   counts  = (int*)p;   p += 64;
  int*   offs    = (int*)p;   p += 64;

  // prep: gate + fcW transpose (keeps fcWt L3-warm right before gemm1)
  k_prep<<<9216, 256, 0, stream>>>(x, gW, gb, idx, wgt, Xh, fcW, fcWt);
  k_route<<<1, 1024, 0, stream>>>(idx, wgt, perm, counts, offs,
                                  out + (size_t)T_TOK * DDIM);
  // gemm1 with oW-transpose in grid tail (runs in gemm1's drain shadow)
  k_gemm1_glu<<<dim3(32, 256), 256, 0, stream>>>(Xh, fcWt, fcb, offs, counts,
                                                 perm, G, oW, outWt);
  k_gemm2_out<<<dim3(8, 128), 256, 0, stream>>>(G, outWt, ob, offs, counts, perm, wgt, out);
}